// Round 7
// baseline (286.897 us; speedup 1.0000x reference)
//
#include <hip/hip_runtime.h>

#define NPT   4096
#define KNN_K 16
#define EPSV  1e-5f

// ---- ws float layout ----
#define W0T_OFF 0                  // [67][64] folded
#define B0_OFF  4288               // [64]
#define W1T_OFF 4352               // [64][64]  (ic-major)
#define B1_OFF  8448               // [64]
#define W2T_OFF 8512               // [64][128] (ic-major)
#define B2_OFF  16704              // [128]
#define IDX_OFF 16832              // int[4*4096*16]
#define XYZ4_OFF 278976            // float4[16384]
#define P_OFF   344512             // float[16384][64]  P = W0p*pts + W0x*xyz + b0
#define Q_OFF   1393088            // float[16384][64]  Q = W0x*xyz

typedef unsigned long long ull;

__global__ void prep_kernel(
    const float* __restrict__ xyz,
    const float* __restrict__ w0, const float* __restrict__ b0, const float* __restrict__ g0,
    const float* __restrict__ be0, const float* __restrict__ rm0, const float* __restrict__ rv0,
    const float* __restrict__ w1, const float* __restrict__ b1, const float* __restrict__ g1,
    const float* __restrict__ be1, const float* __restrict__ rm1, const float* __restrict__ rv1,
    const float* __restrict__ w2, const float* __restrict__ b2, const float* __restrict__ g2,
    const float* __restrict__ be2, const float* __restrict__ rm2, const float* __restrict__ rv2,
    float* __restrict__ ws) {
  int blk = blockIdx.x;
  if (blk < 64) {                        // xyz -> (x,y,z,sq), exact ref arithmetic for knn
    int i = blk * 256 + threadIdx.x;
    const float* p = xyz + i * 3;
    float x = p[0], y = p[1], z = p[2];
    float sq = __fadd_rn(__fadd_rn(__fmul_rn(x, x), __fmul_rn(y, y)), __fmul_rn(z, z));
    ((float4*)(ws + XYZ4_OFF))[i] = make_float4(x, y, z, sq);
    return;
  }
  int i = (blk - 64) * 256 + threadIdx.x;
  if (i < 4288) {                        // w0t: [ic'][oc]
    int oc = i & 63, icp = i >> 6;
    int col = (icp < 64) ? (icp + 3) : (icp - 64);
    float s = g0[oc] * rsqrtf(rv0[oc] + EPSV);
    ws[W0T_OFF + i] = w0[oc * 67 + col] * s;
  } else if (i < 4352) {
    int oc = i - 4288;
    float s = g0[oc] * rsqrtf(rv0[oc] + EPSV);
    ws[i] = (b0[oc] - rm0[oc]) * s + be0[oc];
  } else if (i < 8448) {
    int j = i - 4352; int oc = j & 63, ic = j >> 6;
    float s = g1[oc] * rsqrtf(rv1[oc] + EPSV);
    ws[i] = w1[oc * 64 + ic] * s;
  } else if (i < 8512) {
    int oc = i - 8448;
    float s = g1[oc] * rsqrtf(rv1[oc] + EPSV);
    ws[i] = (b1[oc] - rm1[oc]) * s + be1[oc];
  } else if (i < 16704) {
    int j = i - 8512; int ic = j >> 7, oc = j & 127;
    float s = g2[oc] * rsqrtf(rv2[oc] + EPSV);
    ws[i] = w2[oc * 64 + ic] * s;       // w2t [ic][oc]
  } else if (i < 16832) {
    int oc = i - 16704;
    float s = g2[oc] * rsqrtf(rv2[oc] + EPSV);
    ws[i] = (b2[oc] - rm2[oc]) * s + be2[oc];
  }
}

// P/Q precompute: wave = one point, lane = oc.
__global__ __launch_bounds__(256) void pq_kernel(const float* __restrict__ xyz,
                                                 const float* __restrict__ points,
                                                 float* __restrict__ ws) {
  int tid = threadIdx.x;
  int oc = tid & 63;
  int i = blockIdx.x * 4 + (tid >> 6);
  const float* w0t = ws + W0T_OFF;
  float x = xyz[i * 3], y = xyz[i * 3 + 1], z = xyz[i * 3 + 2];
  float qacc = w0t[64 * 64 + oc] * x;
  qacc = fmaf(w0t[65 * 64 + oc], y, qacc);
  qacc = fmaf(w0t[66 * 64 + oc], z, qacc);
  float acc = ws[B0_OFF + oc] + qacc;
  const float* prow = points + (size_t)i * 64;
#pragma unroll 4
  for (int c = 0; c < 64; ++c) acc = fmaf(w0t[c * 64 + oc], prow[c], acc);
  ws[P_OFF + (size_t)i * 64 + oc] = acc;
  ws[Q_OFF + (size_t)i * 64 + oc] = qacc;
}

__device__ __forceinline__ ull minu64(ull a, ull b) { return a < b ? a : b; }
__device__ __forceinline__ ull maxu64(ull a, ull b) { return a > b ? a : b; }

__device__ __forceinline__ ull bitonic_sort64(ull v, int lane) {
#pragma unroll
  for (int k = 2; k <= 64; k <<= 1) {
#pragma unroll
    for (int j = k >> 1; j > 0; j >>= 1) {
      ull o = __shfl_xor(v, j);
      bool lower = (lane & j) == 0;
      bool up = (lane & k) == 0;
      v = (lower == up) ? minu64(v, o) : maxu64(v, o);
    }
  }
  return v;
}

__device__ __forceinline__ ull bitonic_merge64(ull v, int lane) {
#pragma unroll
  for (int j = 32; j > 0; j >>= 1) {
    ull o = __shfl_xor(v, j);
    v = ((lane & j) == 0) ? minu64(v, o) : maxu64(v, o);
  }
  return v;
}

// Exact R2 insert body. Admitting with a stale (looser) threshold is exact:
// true top-16 keys pass any running threshold; extras fall out in the merge.
__device__ __forceinline__ void insert_key(ull key, ull mask, ull* bufw, int lane,
                                           ull ltmask, int& cnt, ull& R, ull& thresh) {
  if (mask) {
    int pos = cnt + __popcll(mask & ltmask);
    bool pred = (mask >> lane) & 1;
    if (pred) bufw[pos] = key;
    cnt += __popcll(mask);
    if (cnt >= 64) {
      ull v = bufw[lane];
      v = bitonic_sort64(v, lane);
      ull vr = __shfl(v, 63 - lane);
      R = minu64(R, vr);
      R = bitonic_merge64(R, lane);
      thresh = __shfl(R, 15);
      cnt -= 64;
      if (lane < cnt) {
        ull tmp = bufw[64 + lane];
        bufw[lane] = tmp;
      }
    }
  }
}

// KNN: one wave per query, threshold-filter + bitonic flush (R2 semantics),
// inner loop processes 4 independent batches per iteration: 4 ds_read_b128 in
// flight + 4 parallel key chains -> 4x less exposed LDS latency.
__global__ __launch_bounds__(256) void knn_kernel(const float4* __restrict__ cand4,
                                                  int* __restrict__ knnOut) {
  __shared__ __align__(16) float4 tile[1024];
  __shared__ ull buf[4][128];
  int tid = threadIdx.x;
  int lane = tid & 63, w = tid >> 6;
  int b = blockIdx.x >> 10;
  int n = ((blockIdx.x & 1023) << 2) + w;
  const float4* cb = cand4 + b * NPT;

  float4 q = cb[n];
  ull R = ~0ull;
  ull thresh = ~0ull;
  int cnt = 0;
  ull ltmask = (lane == 0) ? 0ull : (~0ull >> (64 - lane));

#pragma unroll 1
  for (int t = 0; t < 4; ++t) {
    __syncthreads();
#pragma unroll
    for (int j = 0; j < 4; ++j) tile[j * 256 + tid] = cb[t * 1024 + j * 256 + tid];
    __syncthreads();
#pragma unroll 1
    for (int i = 0; i < 16; i += 4) {
      // 4 independent LDS reads (issue together; latency amortized)
      float4 c0 = tile[((i + 0) << 6) + lane];
      float4 c1 = tile[((i + 1) << 6) + lane];
      float4 c2 = tile[((i + 2) << 6) + lane];
      float4 c3 = tile[((i + 3) << 6) + lane];
      int m0i = (t << 10) + ((i + 0) << 6) + lane;
      // 4 independent key chains (ILP)
      float dot0 = __fadd_rn(__fadd_rn(__fmul_rn(q.x, c0.x), __fmul_rn(q.y, c0.y)), __fmul_rn(q.z, c0.z));
      float dot1 = __fadd_rn(__fadd_rn(__fmul_rn(q.x, c1.x), __fmul_rn(q.y, c1.y)), __fmul_rn(q.z, c1.z));
      float dot2 = __fadd_rn(__fadd_rn(__fmul_rn(q.x, c2.x), __fmul_rn(q.y, c2.y)), __fmul_rn(q.z, c2.z));
      float dot3 = __fadd_rn(__fadd_rn(__fmul_rn(q.x, c3.x), __fmul_rn(q.y, c3.y)), __fmul_rn(q.z, c3.z));
      float d20 = __fsub_rn(__fadd_rn(q.w, c0.w), __fmul_rn(2.0f, dot0));
      float d21 = __fsub_rn(__fadd_rn(q.w, c1.w), __fmul_rn(2.0f, dot1));
      float d22 = __fsub_rn(__fadd_rn(q.w, c2.w), __fmul_rn(2.0f, dot2));
      float d23 = __fsub_rn(__fadd_rn(q.w, c3.w), __fmul_rn(2.0f, dot3));
      unsigned b0 = __float_as_uint(d20), b1 = __float_as_uint(d21);
      unsigned b2 = __float_as_uint(d22), b3 = __float_as_uint(d23);
      ull k0 = ((ull)(b0 ^ (0x80000000u | (unsigned)((int)b0 >> 31))) << 32) | (unsigned)(m0i);
      ull k1 = ((ull)(b1 ^ (0x80000000u | (unsigned)((int)b1 >> 31))) << 32) | (unsigned)(m0i + 64);
      ull k2 = ((ull)(b2 ^ (0x80000000u | (unsigned)((int)b2 >> 31))) << 32) | (unsigned)(m0i + 128);
      ull k3 = ((ull)(b3 ^ (0x80000000u | (unsigned)((int)b3 >> 31))) << 32) | (unsigned)(m0i + 192);
      // ballots against entry threshold (stale-threshold admission is exact)
      ull ma = __ballot(k0 < thresh);
      ull mb = __ballot(k1 < thresh);
      ull mc = __ballot(k2 < thresh);
      ull md = __ballot(k3 < thresh);
      if (ma | mb | mc | md) {
        insert_key(k0, ma, buf[w], lane, ltmask, cnt, R, thresh);
        insert_key(k1, mb, buf[w], lane, ltmask, cnt, R, thresh);
        insert_key(k2, mc, buf[w], lane, ltmask, cnt, R, thresh);
        insert_key(k3, md, buf[w], lane, ltmask, cnt, R, thresh);
      }
    }
  }
  {
    ull v = (lane < cnt) ? buf[w][lane] : ~0ull;
    v = bitonic_sort64(v, lane);
    ull vr = __shfl(v, 63 - lane);
    R = minu64(R, vr);
    R = bitonic_merge64(R, lane);
  }
  if (lane < KNN_K)
    knnOut[(b * NPT + n) * KNN_K + lane] = (int)(unsigned)(R & 0xFFFFFFFFull);
}

// MLP v2.1 (unchanged from R6, 88.5us): register-tiled GEMM, multiplexed 16KB
// weight buffer, 48 KB LDS -> 3 blocks/CU.
__global__ __launch_bounds__(256) void mlp_kernel(
    const float* __restrict__ wbuf, const int* __restrict__ knn,
    float* __restrict__ out) {
  __shared__ __align__(16) float Ash[4][64 * 32];   // 32 KB
  __shared__ __align__(16) float Wb[64 * 64];       // 16 KB, multiplexed
  int tid = threadIdx.x;
  int lane = tid & 63, w = tid >> 6;
  int c = lane & 7, r = lane >> 3;
  int b = blockIdx.x >> 9;
  int qbase = ((blockIdx.x & 511) << 3) + (w << 1);

  {
    const float4* w1s = (const float4*)(wbuf + W1T_OFF);
    float4* wd = (float4*)Wb;
#pragma unroll
    for (int t = 0; t < 4; ++t) wd[t * 256 + tid] = w1s[t * 256 + tid];
  }

  {
    int p = lane >> 1, half = lane & 1;
    int q = qbase + (p >> 4), k = p & 15;
    int src = knn[(b * NPT + q) * KNN_K + k];
    const float4* Pp = (const float4*)(wbuf + P_OFF + ((size_t)(b * NPT + src) * 64 + half * 32));
    const float4* Qp = (const float4*)(wbuf + Q_OFF + ((size_t)(b * NPT + q) * 64 + half * 32));
    float* Aw = Ash[w];
#pragma unroll
    for (int j = 0; j < 8; ++j) {
      float4 pv = Pp[j];
      float4 qv = Qp[j];
      int ic = half * 32 + j * 4;
      Aw[(ic + 0) * 32 + p] = fmaxf(pv.x - qv.x, 0.0f);
      Aw[(ic + 1) * 32 + p] = fmaxf(pv.y - qv.y, 0.0f);
      Aw[(ic + 2) * 32 + p] = fmaxf(pv.z - qv.z, 0.0f);
      Aw[(ic + 3) * 32 + p] = fmaxf(pv.w - qv.w, 0.0f);
    }
  }
  __syncthreads();

  float* Aw = Ash[w];
  float acc[4][8];

#pragma unroll
  for (int j = 0; j < 8; ++j) {
    float bv = wbuf[B1_OFF + 8 * c + j];
#pragma unroll
    for (int i = 0; i < 4; ++i) acc[i][j] = bv;
  }
#pragma unroll 4
  for (int ic = 0; ic < 64; ++ic) {
    float4 a4 = *(const float4*)(Aw + ic * 32 + 4 * r);
    float4 w40 = *(const float4*)(Wb + ic * 64 + 8 * c);
    float4 w41 = *(const float4*)(Wb + ic * 64 + 8 * c + 4);
    float av[4] = {a4.x, a4.y, a4.z, a4.w};
    float wv[8] = {w40.x, w40.y, w40.z, w40.w, w41.x, w41.y, w41.z, w41.w};
#pragma unroll
    for (int i = 0; i < 4; ++i)
#pragma unroll
      for (int j = 0; j < 8; ++j) acc[i][j] = fmaf(av[i], wv[j], acc[i][j]);
  }
  __builtin_amdgcn_wave_barrier();
#pragma unroll
  for (int j = 0; j < 8; ++j) {
    int oc = 8 * c + j;
    float4 v = make_float4(fmaxf(acc[0][j], 0.0f), fmaxf(acc[1][j], 0.0f),
                           fmaxf(acc[2][j], 0.0f), fmaxf(acc[3][j], 0.0f));
    *(float4*)(Aw + oc * 32 + 4 * r) = v;
  }
  __builtin_amdgcn_wave_barrier();

  int qout = qbase + (lane >> 5);
  bool storer = (lane & 31) < 8;
  float* obase = out + ((size_t)(b * NPT + qout) * 128 + 8 * c);
#pragma unroll 1
  for (int pass = 0; pass < 2; ++pass) {
    __syncthreads();
    {
      const float4* w2s = (const float4*)(wbuf + W2T_OFF);
      float4* wd = (float4*)Wb;
#pragma unroll
      for (int t = 0; t < 4; ++t) {
        int f = t * 256 + tid;
        int row = f >> 4, c4 = f & 15;
        wd[row * 16 + c4] = w2s[row * 32 + pass * 16 + c4];
      }
    }
    __syncthreads();

#pragma unroll
    for (int j = 0; j < 8; ++j) {
      float bv = wbuf[B2_OFF + pass * 64 + 8 * c + j];
#pragma unroll
      for (int i = 0; i < 4; ++i) acc[i][j] = bv;
    }
#pragma unroll 4
    for (int ic = 0; ic < 64; ++ic) {
      float4 a4 = *(const float4*)(Aw + ic * 32 + 4 * r);
      const float* wrow = Wb + ic * 64 + 8 * c;
      float4 w40 = *(const float4*)(wrow);
      float4 w41 = *(const float4*)(wrow + 4);
      float av[4] = {a4.x, a4.y, a4.z, a4.w};
      float wv[8] = {w40.x, w40.y, w40.z, w40.w, w41.x, w41.y, w41.z, w41.w};
#pragma unroll
      for (int i = 0; i < 4; ++i)
#pragma unroll
        for (int j = 0; j < 8; ++j) acc[i][j] = fmaf(av[i], wv[j], acc[i][j]);
    }
    float m[8];
#pragma unroll
    for (int j = 0; j < 8; ++j) {
      float v = fmaxf(fmaxf(acc[0][j], acc[1][j]), fmaxf(acc[2][j], acc[3][j]));
      v = fmaxf(v, 0.0f);
      v = fmaxf(v, __shfl_xor(v, 8));
      v = fmaxf(v, __shfl_xor(v, 16));
      m[j] = v;
    }
    if (storer) {
      *(float4*)(obase + pass * 64)     = make_float4(m[0], m[1], m[2], m[3]);
      *(float4*)(obase + pass * 64 + 4) = make_float4(m[4], m[5], m[6], m[7]);
    }
  }
}

extern "C" void kernel_launch(void* const* d_in, const int* in_sizes, int n_in,
                              void* d_out, int out_size, void* d_ws, size_t ws_size,
                              hipStream_t stream) {
  const float* xyz    = (const float*)d_in[0];
  const float* points = (const float*)d_in[1];
  float* wsF = (float*)d_ws;
  int* idxBuf = (int*)(wsF + IDX_OFF);
  const float4* cand4 = (const float4*)(wsF + XYZ4_OFF);

  prep_kernel<<<130, 256, 0, stream>>>(
      xyz,
      (const float*)d_in[2],  (const float*)d_in[3],  (const float*)d_in[4],
      (const float*)d_in[5],  (const float*)d_in[6],  (const float*)d_in[7],
      (const float*)d_in[8],  (const float*)d_in[9],  (const float*)d_in[10],
      (const float*)d_in[11], (const float*)d_in[12], (const float*)d_in[13],
      (const float*)d_in[14], (const float*)d_in[15], (const float*)d_in[16],
      (const float*)d_in[17], (const float*)d_in[18], (const float*)d_in[19],
      wsF);
  pq_kernel<<<4096, 256, 0, stream>>>(xyz, points, wsF);
  knn_kernel<<<4096, 256, 0, stream>>>(cand4, idxBuf);
  mlp_kernel<<<2048, 256, 0, stream>>>(wsF, idxBuf, (float*)d_out);
}

// Round 8
// 283.593 us; speedup vs baseline: 1.0116x; 1.0116x over previous
//
#include <hip/hip_runtime.h>

#define NPT   4096
#define KNN_K 16
#define EPSV  1e-5f

// ---- ws float layout ----
#define W0T_OFF 0                  // [67][64] folded
#define B0_OFF  4288               // [64]
#define W1T_OFF 4352               // [64][64]  (ic-major)
#define B1_OFF  8448               // [64]
#define W2T_OFF 8512               // [64][128] (ic-major)
#define B2_OFF  16704              // [128]
#define IDX_OFF 16832              // int[4*4096*16]
#define XYZ4_OFF 278976            // float4[16384]
#define P_OFF   344512             // float[16384][64]  P = W0p*pts + W0x*xyz + b0
#define Q_OFF   1393088            // float[16384][64]  Q = W0x*xyz

typedef unsigned long long ull;

__global__ void prep_kernel(
    const float* __restrict__ xyz,
    const float* __restrict__ w0, const float* __restrict__ b0, const float* __restrict__ g0,
    const float* __restrict__ be0, const float* __restrict__ rm0, const float* __restrict__ rv0,
    const float* __restrict__ w1, const float* __restrict__ b1, const float* __restrict__ g1,
    const float* __restrict__ be1, const float* __restrict__ rm1, const float* __restrict__ rv1,
    const float* __restrict__ w2, const float* __restrict__ b2, const float* __restrict__ g2,
    const float* __restrict__ be2, const float* __restrict__ rm2, const float* __restrict__ rv2,
    float* __restrict__ ws) {
  int blk = blockIdx.x;
  if (blk < 64) {                        // xyz -> (x,y,z,sq), exact ref arithmetic for knn
    int i = blk * 256 + threadIdx.x;
    const float* p = xyz + i * 3;
    float x = p[0], y = p[1], z = p[2];
    float sq = __fadd_rn(__fadd_rn(__fmul_rn(x, x), __fmul_rn(y, y)), __fmul_rn(z, z));
    ((float4*)(ws + XYZ4_OFF))[i] = make_float4(x, y, z, sq);
    return;
  }
  int i = (blk - 64) * 256 + threadIdx.x;
  if (i < 4288) {                        // w0t: [ic'][oc]
    int oc = i & 63, icp = i >> 6;
    int col = (icp < 64) ? (icp + 3) : (icp - 64);
    float s = g0[oc] * rsqrtf(rv0[oc] + EPSV);
    ws[W0T_OFF + i] = w0[oc * 67 + col] * s;
  } else if (i < 4352) {
    int oc = i - 4288;
    float s = g0[oc] * rsqrtf(rv0[oc] + EPSV);
    ws[i] = (b0[oc] - rm0[oc]) * s + be0[oc];
  } else if (i < 8448) {
    int j = i - 4352; int oc = j & 63, ic = j >> 6;
    float s = g1[oc] * rsqrtf(rv1[oc] + EPSV);
    ws[i] = w1[oc * 64 + ic] * s;
  } else if (i < 8512) {
    int oc = i - 8448;
    float s = g1[oc] * rsqrtf(rv1[oc] + EPSV);
    ws[i] = (b1[oc] - rm1[oc]) * s + be1[oc];
  } else if (i < 16704) {
    int j = i - 8512; int ic = j >> 7, oc = j & 127;
    float s = g2[oc] * rsqrtf(rv2[oc] + EPSV);
    ws[i] = w2[oc * 64 + ic] * s;       // w2t [ic][oc]
  } else if (i < 16832) {
    int oc = i - 16704;
    float s = g2[oc] * rsqrtf(rv2[oc] + EPSV);
    ws[i] = (b2[oc] - rm2[oc]) * s + be2[oc];
  }
}

// P/Q precompute: wave = one point, lane = oc.
__global__ __launch_bounds__(256) void pq_kernel(const float* __restrict__ xyz,
                                                 const float* __restrict__ points,
                                                 float* __restrict__ ws) {
  int tid = threadIdx.x;
  int oc = tid & 63;
  int i = blockIdx.x * 4 + (tid >> 6);
  const float* w0t = ws + W0T_OFF;
  float x = xyz[i * 3], y = xyz[i * 3 + 1], z = xyz[i * 3 + 2];
  float qacc = w0t[64 * 64 + oc] * x;
  qacc = fmaf(w0t[65 * 64 + oc], y, qacc);
  qacc = fmaf(w0t[66 * 64 + oc], z, qacc);
  float acc = ws[B0_OFF + oc] + qacc;
  const float* prow = points + (size_t)i * 64;
#pragma unroll 4
  for (int c = 0; c < 64; ++c) acc = fmaf(w0t[c * 64 + oc], prow[c], acc);
  ws[P_OFF + (size_t)i * 64 + oc] = acc;
  ws[Q_OFF + (size_t)i * 64 + oc] = qacc;
}

__device__ __forceinline__ ull minu64(ull a, ull b) { return a < b ? a : b; }
__device__ __forceinline__ ull maxu64(ull a, ull b) { return a > b ? a : b; }

__device__ __forceinline__ ull bitonic_sort64(ull v, int lane) {
#pragma unroll
  for (int k = 2; k <= 64; k <<= 1) {
#pragma unroll
    for (int j = k >> 1; j > 0; j >>= 1) {
      ull o = __shfl_xor(v, j);
      bool lower = (lane & j) == 0;
      bool up = (lane & k) == 0;
      v = (lower == up) ? minu64(v, o) : maxu64(v, o);
    }
  }
  return v;
}

__device__ __forceinline__ ull bitonic_merge64(ull v, int lane) {
#pragma unroll
  for (int j = 32; j > 0; j >>= 1) {
    ull o = __shfl_xor(v, j);
    v = ((lane & j) == 0) ? minu64(v, o) : maxu64(v, o);
  }
  return v;
}

// monotone fp32->uint key map (forward) and its inverse
__device__ __forceinline__ unsigned fkey(float f) {
  unsigned b = __float_as_uint(f);
  return b ^ (0x80000000u | (unsigned)((int)b >> 31));
}
__device__ __forceinline__ float fkey_inv(unsigned fk) {
  unsigned b = (fk & 0x80000000u) ? (fk ^ 0x80000000u) : ~fk;
  return __uint_as_float(b);
}

// Insert body (R2 semantics). Admitting with a stale/looser threshold is
// exact: true top-16 keys pass any running threshold; extras are discarded by
// the merge. On flush, th_f := d2-float of the 16th-smallest key.
__device__ __forceinline__ void insert_key(ull key, ull mask, ull* bufw, int lane,
                                           ull ltmask, int& cnt, ull& R, float& th_f) {
  if (mask) {
    int pos = cnt + __popcll(mask & ltmask);
    bool pred = (mask >> lane) & 1;
    if (pred) bufw[pos] = key;
    cnt += __popcll(mask);
    if (cnt >= 64) {
      ull v = bufw[lane];
      v = bitonic_sort64(v, lane);
      ull vr = __shfl(v, 63 - lane);
      R = minu64(R, vr);
      R = bitonic_merge64(R, lane);
      ull th = __shfl(R, 15);
      th_f = fkey_inv((unsigned)(th >> 32));
      cnt -= 64;
      if (lane < cnt) {
        ull tmp = bufw[64 + lane];
        bufw[lane] = tmp;
      }
    }
  }
}

// KNN: one wave per query; 4 independent batches/iter (ILP). Admission is a
// pure fp32 compare d2 <= th_f (superset of key<thresh: uint key order
// refines float order; float-tie extras merge away). 64-bit keys built only
// on the rare admit path. Neighbor sets bit-identical to the reference.
__global__ __launch_bounds__(256) void knn_kernel(const float4* __restrict__ cand4,
                                                  int* __restrict__ knnOut) {
  __shared__ __align__(16) float4 tile[1024];
  __shared__ ull buf[4][128];
  int tid = threadIdx.x;
  int lane = tid & 63, w = tid >> 6;
  int b = blockIdx.x >> 10;
  int n = ((blockIdx.x & 1023) << 2) + w;
  const float4* cb = cand4 + b * NPT;

  float4 q = cb[n];
  ull R = ~0ull;
  float th_f = __int_as_float(0x7F800000);      // +inf: admit all until 1st flush
  int cnt = 0;
  ull ltmask = (lane == 0) ? 0ull : (~0ull >> (64 - lane));

#pragma unroll 1
  for (int t = 0; t < 4; ++t) {
    __syncthreads();
#pragma unroll
    for (int j = 0; j < 4; ++j) tile[j * 256 + tid] = cb[t * 1024 + j * 256 + tid];
    __syncthreads();
#pragma unroll 1
    for (int i = 0; i < 16; i += 4) {
      // 4 independent LDS reads + 4 independent d2 chains (exact ref arith)
      float4 c0 = tile[((i + 0) << 6) + lane];
      float4 c1 = tile[((i + 1) << 6) + lane];
      float4 c2 = tile[((i + 2) << 6) + lane];
      float4 c3 = tile[((i + 3) << 6) + lane];
      int m0i = (t << 10) + ((i + 0) << 6) + lane;
      float dot0 = __fadd_rn(__fadd_rn(__fmul_rn(q.x, c0.x), __fmul_rn(q.y, c0.y)), __fmul_rn(q.z, c0.z));
      float dot1 = __fadd_rn(__fadd_rn(__fmul_rn(q.x, c1.x), __fmul_rn(q.y, c1.y)), __fmul_rn(q.z, c1.z));
      float dot2 = __fadd_rn(__fadd_rn(__fmul_rn(q.x, c2.x), __fmul_rn(q.y, c2.y)), __fmul_rn(q.z, c2.z));
      float dot3 = __fadd_rn(__fadd_rn(__fmul_rn(q.x, c3.x), __fmul_rn(q.y, c3.y)), __fmul_rn(q.z, c3.z));
      float d20 = __fsub_rn(__fadd_rn(q.w, c0.w), __fmul_rn(2.0f, dot0));
      float d21 = __fsub_rn(__fadd_rn(q.w, c1.w), __fmul_rn(2.0f, dot1));
      float d22 = __fsub_rn(__fadd_rn(q.w, c2.w), __fmul_rn(2.0f, dot2));
      float d23 = __fsub_rn(__fadd_rn(q.w, c3.w), __fmul_rn(2.0f, dot3));
      // fp32 fast-path admission test
      ull ma = __ballot(d20 <= th_f);
      ull mb = __ballot(d21 <= th_f);
      ull mc = __ballot(d22 <= th_f);
      ull md = __ballot(d23 <= th_f);
      if (ma | mb | mc | md) {                  // rare: build keys + insert
        ull k0 = ((ull)fkey(d20) << 32) | (unsigned)(m0i);
        ull k1 = ((ull)fkey(d21) << 32) | (unsigned)(m0i + 64);
        ull k2 = ((ull)fkey(d22) << 32) | (unsigned)(m0i + 128);
        ull k3 = ((ull)fkey(d23) << 32) | (unsigned)(m0i + 192);
        insert_key(k0, ma, buf[w], lane, ltmask, cnt, R, th_f);
        insert_key(k1, mb, buf[w], lane, ltmask, cnt, R, th_f);
        insert_key(k2, mc, buf[w], lane, ltmask, cnt, R, th_f);
        insert_key(k3, md, buf[w], lane, ltmask, cnt, R, th_f);
      }
    }
  }
  {
    ull v = (lane < cnt) ? buf[w][lane] : ~0ull;
    v = bitonic_sort64(v, lane);
    ull vr = __shfl(v, 63 - lane);
    R = minu64(R, vr);
    R = bitonic_merge64(R, lane);
  }
  if (lane < KNN_K)
    knnOut[(b * NPT + n) * KNN_K + lane] = (int)(unsigned)(R & 0xFFFFFFFFull);
}

// MLP v2.1 (frozen since R6, 88.5us): register-tiled GEMM, multiplexed 16KB
// weight buffer, 48 KB LDS -> 3 blocks/CU.
__global__ __launch_bounds__(256) void mlp_kernel(
    const float* __restrict__ wbuf, const int* __restrict__ knn,
    float* __restrict__ out) {
  __shared__ __align__(16) float Ash[4][64 * 32];   // 32 KB
  __shared__ __align__(16) float Wb[64 * 64];       // 16 KB, multiplexed
  int tid = threadIdx.x;
  int lane = tid & 63, w = tid >> 6;
  int c = lane & 7, r = lane >> 3;
  int b = blockIdx.x >> 9;
  int qbase = ((blockIdx.x & 511) << 3) + (w << 1);

  {
    const float4* w1s = (const float4*)(wbuf + W1T_OFF);
    float4* wd = (float4*)Wb;
#pragma unroll
    for (int t = 0; t < 4; ++t) wd[t * 256 + tid] = w1s[t * 256 + tid];
  }

  {
    int p = lane >> 1, half = lane & 1;
    int q = qbase + (p >> 4), k = p & 15;
    int src = knn[(b * NPT + q) * KNN_K + k];
    const float4* Pp = (const float4*)(wbuf + P_OFF + ((size_t)(b * NPT + src) * 64 + half * 32));
    const float4* Qp = (const float4*)(wbuf + Q_OFF + ((size_t)(b * NPT + q) * 64 + half * 32));
    float* Aw = Ash[w];
#pragma unroll
    for (int j = 0; j < 8; ++j) {
      float4 pv = Pp[j];
      float4 qv = Qp[j];
      int ic = half * 32 + j * 4;
      Aw[(ic + 0) * 32 + p] = fmaxf(pv.x - qv.x, 0.0f);
      Aw[(ic + 1) * 32 + p] = fmaxf(pv.y - qv.y, 0.0f);
      Aw[(ic + 2) * 32 + p] = fmaxf(pv.z - qv.z, 0.0f);
      Aw[(ic + 3) * 32 + p] = fmaxf(pv.w - qv.w, 0.0f);
    }
  }
  __syncthreads();

  float* Aw = Ash[w];
  float acc[4][8];

#pragma unroll
  for (int j = 0; j < 8; ++j) {
    float bv = wbuf[B1_OFF + 8 * c + j];
#pragma unroll
    for (int i = 0; i < 4; ++i) acc[i][j] = bv;
  }
#pragma unroll 4
  for (int ic = 0; ic < 64; ++ic) {
    float4 a4 = *(const float4*)(Aw + ic * 32 + 4 * r);
    float4 w40 = *(const float4*)(Wb + ic * 64 + 8 * c);
    float4 w41 = *(const float4*)(Wb + ic * 64 + 8 * c + 4);
    float av[4] = {a4.x, a4.y, a4.z, a4.w};
    float wv[8] = {w40.x, w40.y, w40.z, w40.w, w41.x, w41.y, w41.z, w41.w};
#pragma unroll
    for (int i = 0; i < 4; ++i)
#pragma unroll
      for (int j = 0; j < 8; ++j) acc[i][j] = fmaf(av[i], wv[j], acc[i][j]);
  }
  __builtin_amdgcn_wave_barrier();
#pragma unroll
  for (int j = 0; j < 8; ++j) {
    int oc = 8 * c + j;
    float4 v = make_float4(fmaxf(acc[0][j], 0.0f), fmaxf(acc[1][j], 0.0f),
                           fmaxf(acc[2][j], 0.0f), fmaxf(acc[3][j], 0.0f));
    *(float4*)(Aw + oc * 32 + 4 * r) = v;
  }
  __builtin_amdgcn_wave_barrier();

  int qout = qbase + (lane >> 5);
  bool storer = (lane & 31) < 8;
  float* obase = out + ((size_t)(b * NPT + qout) * 128 + 8 * c);
#pragma unroll 1
  for (int pass = 0; pass < 2; ++pass) {
    __syncthreads();
    {
      const float4* w2s = (const float4*)(wbuf + W2T_OFF);
      float4* wd = (float4*)Wb;
#pragma unroll
      for (int t = 0; t < 4; ++t) {
        int f = t * 256 + tid;
        int row = f >> 4, c4 = f & 15;
        wd[row * 16 + c4] = w2s[row * 32 + pass * 16 + c4];
      }
    }
    __syncthreads();

#pragma unroll
    for (int j = 0; j < 8; ++j) {
      float bv = wbuf[B2_OFF + pass * 64 + 8 * c + j];
#pragma unroll
      for (int i = 0; i < 4; ++i) acc[i][j] = bv;
    }
#pragma unroll 4
    for (int ic = 0; ic < 64; ++ic) {
      float4 a4 = *(const float4*)(Aw + ic * 32 + 4 * r);
      const float* wrow = Wb + ic * 64 + 8 * c;
      float4 w40 = *(const float4*)(wrow);
      float4 w41 = *(const float4*)(wrow + 4);
      float av[4] = {a4.x, a4.y, a4.z, a4.w};
      float wv[8] = {w40.x, w40.y, w40.z, w40.w, w41.x, w41.y, w41.z, w41.w};
#pragma unroll
      for (int i = 0; i < 4; ++i)
#pragma unroll
        for (int j = 0; j < 8; ++j) acc[i][j] = fmaf(av[i], wv[j], acc[i][j]);
    }
    float m[8];
#pragma unroll
    for (int j = 0; j < 8; ++j) {
      float v = fmaxf(fmaxf(acc[0][j], acc[1][j]), fmaxf(acc[2][j], acc[3][j]));
      v = fmaxf(v, 0.0f);
      v = fmaxf(v, __shfl_xor(v, 8));
      v = fmaxf(v, __shfl_xor(v, 16));
      m[j] = v;
    }
    if (storer) {
      *(float4*)(obase + pass * 64)     = make_float4(m[0], m[1], m[2], m[3]);
      *(float4*)(obase + pass * 64 + 4) = make_float4(m[4], m[5], m[6], m[7]);
    }
  }
}

extern "C" void kernel_launch(void* const* d_in, const int* in_sizes, int n_in,
                              void* d_out, int out_size, void* d_ws, size_t ws_size,
                              hipStream_t stream) {
  const float* xyz    = (const float*)d_in[0];
  const float* points = (const float*)d_in[1];
  float* wsF = (float*)d_ws;
  int* idxBuf = (int*)(wsF + IDX_OFF);
  const float4* cand4 = (const float4*)(wsF + XYZ4_OFF);

  prep_kernel<<<130, 256, 0, stream>>>(
      xyz,
      (const float*)d_in[2],  (const float*)d_in[3],  (const float*)d_in[4],
      (const float*)d_in[5],  (const float*)d_in[6],  (const float*)d_in[7],
      (const float*)d_in[8],  (const float*)d_in[9],  (const float*)d_in[10],
      (const float*)d_in[11], (const float*)d_in[12], (const float*)d_in[13],
      (const float*)d_in[14], (const float*)d_in[15], (const float*)d_in[16],
      (const float*)d_in[17], (const float*)d_in[18], (const float*)d_in[19],
      wsF);
  pq_kernel<<<4096, 256, 0, stream>>>(xyz, points, wsF);
  knn_kernel<<<4096, 256, 0, stream>>>(cand4, idxBuf);
  mlp_kernel<<<2048, 256, 0, stream>>>(wsF, idxBuf, (float*)d_out);
}